// Round 3
// baseline (395.369 us; speedup 1.0000x reference)
//
#include <hip/hip_runtime.h>

namespace {

constexpr int BATCH = 8192;
constexpr int EMB   = 128;
constexpr int HID   = 512;
constexpr int NMOD  = 64;
constexpr int CAP   = 256;   // Bin(8192,1/64) max ~170 << 256 (validated r1/r2)
constexpr int GRID  = 512;
constexpr float WB  = 1.0f / (7.0f * 0.5f);  // 2/7

// ws layout (float offsets)
constexpr size_t OFF_WT   = 0;                    // 64*128*128 [i][o] k-major
constexpr size_t OFF_X0   = 1048576;
constexpr size_t OFF_X1   = 2 * 1048576;
constexpr size_t OFF_H    = 3 * 1048576;          // 8192*512
constexpr size_t OFF_W1T  = 7 * 1048576;          // 128*512  [k][col]
constexpr size_t OFF_W2T  = OFF_W1T + 65536;      // 512*64   [k][col]
constexpr size_t OFF_CNT  = OFF_W2T + 32768;      // 192 ints
constexpr size_t OFF_BAR  = OFF_CNT + 192;        // 32 ints (barrier slots)
constexpr size_t OFF_BKT  = OFF_CNT + 256;        // 3*64*CAP ints
constexpr size_t OFF_PART = OFF_BKT + 49152;      // 4*8192*64 partials
// end ~9.6M floats (38.3 MB) << ws_size (~400 MB)

// device-scope grid barrier; bar[] zeroed via hipMemsetAsync each call
__device__ __forceinline__ void gbar(int* bar, int slot) {
  __syncthreads();
  if (threadIdx.x == 0) {
    __threadfence();
    atomicAdd(&bar[slot], 1);
    while (__hip_atomic_load(&bar[slot], __ATOMIC_RELAXED,
                             __HIP_MEMORY_SCOPE_AGENT) < GRID) {
      __builtin_amdgcn_s_sleep(2);
    }
    __threadfence();
  }
  __syncthreads();
}

// ---------------- hop phase: per-module 64x64 GEMM tiles -------------------
template <int HOP>
__device__ __forceinline__ void hop_phase(const float* __restrict__ E,
                                          const int* __restrict__ eids,
                                          float* __restrict__ ws, char* smem) {
  float* wsm = (float*)smem;                    // [64][64]  16384 B
  float* xs  = (float*)(smem + 16384);          // [64][129] 33024 B
  int* rows  = (int*)(smem + 16384 + 33024);    // 256 B
  const int bx = blockIdx.x;
  const int m = bx >> 3, sl = (bx >> 1) & 3, ch = bx & 1;
  const int cn = ((const int*)(ws + OFF_CNT))[HOP * NMOD + m];
  const int r0 = sl * 64;
  if (r0 >= cn) return;  // block-uniform; gbar happens in caller
  const int nr = min(64, cn - r0);
  const int c0 = ch * 64;
  const float* WT = ws + OFF_WT + (size_t)m * 16384;
  const int* bkt = (const int*)(ws + OFF_BKT) + (HOP * NMOD + m) * CAP;
  const float* Xprev = ws + (HOP == 1 ? OFF_X0 : OFF_X1);
  float* Xnext = ws + (HOP == 1 ? OFF_X1 : OFF_X0);
  const int tid = threadIdx.x;

  if (tid < nr) rows[tid] = bkt[r0 + tid];
  __syncthreads();
  for (int e = tid; e < 64 * 32; e += 256) {
    const int row = e >> 5, i4 = e & 31;
    if (row < nr) {
      const int b = rows[row];
      const float* src = (HOP == 0) ? (E + (size_t)eids[b * 4] * EMB)
                                    : (Xprev + (size_t)b * EMB);
      const float4 v = *(const float4*)&src[4 * i4];
      float* d = &xs[row * 129 + 4 * i4];
      d[0] = v.x; d[1] = v.y; d[2] = v.z; d[3] = v.w;
    }
  }

  const int tr = tid >> 4, tc = tid & 15;
  float acc[4][4] = {};
#pragma unroll
  for (int kh = 0; kh < 2; ++kh) {
    __syncthreads();  // xs ready (kh=0) / prev compute done (kh=1)
    for (int e = tid; e < 64 * 16; e += 256) {
      const int kk = e >> 4, c4 = e & 15;
      *(float4*)&wsm[kk * 64 + 4 * c4] =
          *(const float4*)&WT[(size_t)(kh * 64 + kk) * 128 + c0 + 4 * c4];
    }
    __syncthreads();
    const float* xk = xs + kh * 64;
#pragma unroll 4
    for (int kk = 0; kk < 64; ++kk) {
      const float4 bv = *(const float4*)&wsm[kk * 64 + tc * 4];
      const float a0 = xk[(tr * 4 + 0) * 129 + kk];
      const float a1 = xk[(tr * 4 + 1) * 129 + kk];
      const float a2 = xk[(tr * 4 + 2) * 129 + kk];
      const float a3 = xk[(tr * 4 + 3) * 129 + kk];
      acc[0][0] = fmaf(a0, bv.x, acc[0][0]); acc[0][1] = fmaf(a0, bv.y, acc[0][1]);
      acc[0][2] = fmaf(a0, bv.z, acc[0][2]); acc[0][3] = fmaf(a0, bv.w, acc[0][3]);
      acc[1][0] = fmaf(a1, bv.x, acc[1][0]); acc[1][1] = fmaf(a1, bv.y, acc[1][1]);
      acc[1][2] = fmaf(a1, bv.z, acc[1][2]); acc[1][3] = fmaf(a1, bv.w, acc[1][3]);
      acc[2][0] = fmaf(a2, bv.x, acc[2][0]); acc[2][1] = fmaf(a2, bv.y, acc[2][1]);
      acc[2][2] = fmaf(a2, bv.z, acc[2][2]); acc[2][3] = fmaf(a2, bv.w, acc[2][3]);
      acc[3][0] = fmaf(a3, bv.x, acc[3][0]); acc[3][1] = fmaf(a3, bv.y, acc[3][1]);
      acc[3][2] = fmaf(a3, bv.z, acc[3][2]); acc[3][3] = fmaf(a3, bv.w, acc[3][3]);
    }
  }

#pragma unroll
  for (int p = 0; p < 4; ++p) {
    const int row = tr * 4 + p;
    if (row < nr) {
      const int b = rows[row];
      const float4 bias =
          *(const float4*)&E[(size_t)eids[b * 4 + HOP + 1] * EMB + c0 + tc * 4];
      float4 o;
      o.x = fmaxf(acc[p][0] + bias.x, 0.f);
      o.y = fmaxf(acc[p][1] + bias.y, 0.f);
      o.z = fmaxf(acc[p][2] + bias.z, 0.f);
      o.w = fmaxf(acc[p][3] + bias.w, 0.f);
      if (HOP == 2) {
        o.x = (1.f - WB) * bias.x + WB * o.x;
        o.y = (1.f - WB) * bias.y + WB * o.y;
        o.z = (1.f - WB) * bias.z + WB * o.z;
        o.w = (1.f - WB) * bias.w + WB * o.w;
      }
      *(float4*)&Xnext[(size_t)b * EMB + c0 + tc * 4] = o;
    }
  }
}

// ---------------- the fused persistent kernel ------------------------------
__global__ __launch_bounds__(256, 3) void k_fused(
    const float* __restrict__ E, const float* __restrict__ Wm,
    const float* __restrict__ W1, const float* __restrict__ b1,
    const float* __restrict__ W2, const float* __restrict__ b2,
    const int* __restrict__ eids, const int* __restrict__ mids,
    float* __restrict__ ws, float* __restrict__ out) {
  __shared__ __align__(16) char smem[49664];
  int* bar = (int*)(ws + OFF_BAR);
  const int bx = blockIdx.x;
  const int tid = threadIdx.x;

  // ---- P0: weight transposes + bucket scatter (cnt pre-zeroed by memset) --
  if (bx < 64) {  // W_mods[bx] 128x128 -> WT [i][o], in two half-tiles
    float* t = (float*)smem;  // [64][129]
    const float* src = Wm + (size_t)bx * 16384;
    float* dst = ws + OFF_WT + (size_t)bx * 16384;
#pragma unroll
    for (int h = 0; h < 2; ++h) {
      __syncthreads();
      for (int e = tid; e < 64 * 128; e += 256) {
        const int o = e >> 7, i = e & 127;
        t[o * 129 + i] = src[(size_t)(h * 64 + o) * 128 + i];
      }
      __syncthreads();
      for (int e = tid; e < 128 * 64; e += 256) {
        const int i = e >> 6, oo = e & 63;
        dst[(size_t)i * 128 + h * 64 + oo] = t[oo * 129 + i];
      }
    }
  } else if (bx < 72) {  // W1 [512][128] -> W1T [128][512]
    const int j = bx - 64;
    float* t = (float*)smem;  // [64][129]
    for (int e = tid; e < 64 * 128; e += 256) {
      const int r = e >> 7, i = e & 127;
      t[r * 129 + i] = W1[(size_t)(j * 64 + r) * 128 + i];
    }
    __syncthreads();
    float* W1T = ws + OFF_W1T;
    for (int e = tid; e < 128 * 16; e += 256) {
      const int i = e >> 4, r4 = e & 15;
      float4 v;
      v.x = t[(4 * r4 + 0) * 129 + i];
      v.y = t[(4 * r4 + 1) * 129 + i];
      v.z = t[(4 * r4 + 2) * 129 + i];
      v.w = t[(4 * r4 + 3) * 129 + i];
      *(float4*)&W1T[(size_t)i * 512 + j * 64 + 4 * r4] = v;
    }
  } else if (bx < 80) {  // W2 [64][512] -> W2T [512][64]
    const int j = bx - 72;
    float* t = (float*)smem;  // [64][65]
    for (int e = tid; e < 64 * 64; e += 256) {
      const int o = e >> 6, k = e & 63;
      t[o * 65 + k] = W2[(size_t)o * 512 + j * 64 + k];
    }
    __syncthreads();
    float* W2T = ws + OFF_W2T;
    for (int e = tid; e < 64 * 16; e += 256) {
      const int k = e >> 4, o4 = e & 15;
      float4 v;
      v.x = t[(4 * o4 + 0) * 65 + k];
      v.y = t[(4 * o4 + 1) * 65 + k];
      v.z = t[(4 * o4 + 2) * 65 + k];
      v.w = t[(4 * o4 + 3) * 65 + k];
      *(float4*)&W2T[(size_t)(j * 64 + k) * 64 + 4 * o4] = v;
    }
  } else if (bx < 176) {  // bucket scatter
    const int idx = (bx - 80) * 256 + tid;
    if (idx < BATCH * 3) {
      const int b = idx / 3, h = idx - b * 3;
      const int m = mids[idx];
      int* cnt = (int*)(ws + OFF_CNT);
      int* bkt = (int*)(ws + OFF_BKT);
      const int pos = atomicAdd(&cnt[h * NMOD + m], 1);
      bkt[(h * NMOD + m) * CAP + pos] = b;
    }
  }
  gbar(bar, 0);

  // ---- P1-P3: hops --------------------------------------------------------
  hop_phase<0>(E, eids, ws, smem); gbar(bar, 1);
  hop_phase<1>(E, eids, ws, smem); gbar(bar, 2);
  hop_phase<2>(E, eids, ws, smem); gbar(bar, 3);

  // ---- P4: mlp1  H = relu(X0 @ W1T + b1), 64x128 tiles --------------------
  {
    float* wsm = (float*)smem;            // [32][128] 16384 B
    float* xs  = (float*)(smem + 16384);  // [64][129] 33024 B
    const int rt = bx >> 2, ct = bx & 3;
    const float* X = ws + OFF_X0;
    const float* W1T = ws + OFF_W1T + ct * 128;
    float* H = ws + OFF_H;
    for (int e = tid; e < 64 * 32; e += 256) {
      const int row = e >> 5, i4 = e & 31;
      const float4 v = *(const float4*)&X[(size_t)(rt * 64 + row) * EMB + 4 * i4];
      float* d = &xs[row * 129 + 4 * i4];
      d[0] = v.x; d[1] = v.y; d[2] = v.z; d[3] = v.w;
    }
    const int tr = tid >> 4, tc = tid & 15;
    float acc[4][8] = {};
#pragma unroll
    for (int kq = 0; kq < 4; ++kq) {
      __syncthreads();
      for (int e = tid; e < 32 * 32; e += 256) {
        const int kk = e >> 5, c4 = e & 31;
        *(float4*)&wsm[kk * 128 + 4 * c4] =
            *(const float4*)&W1T[(size_t)(kq * 32 + kk) * 512 + 4 * c4];
      }
      __syncthreads();
#pragma unroll 2
      for (int kk = 0; kk < 32; ++kk) {
        const int k = kq * 32 + kk;
        const float4 b0 = *(const float4*)&wsm[kk * 128 + tc * 4];
        const float4 b1v = *(const float4*)&wsm[kk * 128 + 64 + tc * 4];
        const float a0 = xs[(tr * 4 + 0) * 129 + k];
        const float a1 = xs[(tr * 4 + 1) * 129 + k];
        const float a2 = xs[(tr * 4 + 2) * 129 + k];
        const float a3 = xs[(tr * 4 + 3) * 129 + k];
        acc[0][0] = fmaf(a0, b0.x, acc[0][0]); acc[0][1] = fmaf(a0, b0.y, acc[0][1]);
        acc[0][2] = fmaf(a0, b0.z, acc[0][2]); acc[0][3] = fmaf(a0, b0.w, acc[0][3]);
        acc[0][4] = fmaf(a0, b1v.x, acc[0][4]); acc[0][5] = fmaf(a0, b1v.y, acc[0][5]);
        acc[0][6] = fmaf(a0, b1v.z, acc[0][6]); acc[0][7] = fmaf(a0, b1v.w, acc[0][7]);
        acc[1][0] = fmaf(a1, b0.x, acc[1][0]); acc[1][1] = fmaf(a1, b0.y, acc[1][1]);
        acc[1][2] = fmaf(a1, b0.z, acc[1][2]); acc[1][3] = fmaf(a1, b0.w, acc[1][3]);
        acc[1][4] = fmaf(a1, b1v.x, acc[1][4]); acc[1][5] = fmaf(a1, b1v.y, acc[1][5]);
        acc[1][6] = fmaf(a1, b1v.z, acc[1][6]); acc[1][7] = fmaf(a1, b1v.w, acc[1][7]);
        acc[2][0] = fmaf(a2, b0.x, acc[2][0]); acc[2][1] = fmaf(a2, b0.y, acc[2][1]);
        acc[2][2] = fmaf(a2, b0.z, acc[2][2]); acc[2][3] = fmaf(a2, b0.w, acc[2][3]);
        acc[2][4] = fmaf(a2, b1v.x, acc[2][4]); acc[2][5] = fmaf(a2, b1v.y, acc[2][5]);
        acc[2][6] = fmaf(a2, b1v.z, acc[2][6]); acc[2][7] = fmaf(a2, b1v.w, acc[2][7]);
        acc[3][0] = fmaf(a3, b0.x, acc[3][0]); acc[3][1] = fmaf(a3, b0.y, acc[3][1]);
        acc[3][2] = fmaf(a3, b0.z, acc[3][2]); acc[3][3] = fmaf(a3, b0.w, acc[3][3]);
        acc[3][4] = fmaf(a3, b1v.x, acc[3][4]); acc[3][5] = fmaf(a3, b1v.y, acc[3][5]);
        acc[3][6] = fmaf(a3, b1v.z, acc[3][6]); acc[3][7] = fmaf(a3, b1v.w, acc[3][7]);
      }
    }
    const float4 bb0 = *(const float4*)&b1[ct * 128 + tc * 4];
    const float4 bb1 = *(const float4*)&b1[ct * 128 + 64 + tc * 4];
#pragma unroll
    for (int p = 0; p < 4; ++p) {
      const size_t row = (size_t)(rt * 64 + tr * 4 + p);
      float4 o0, o1;
      o0.x = fmaxf(acc[p][0] + bb0.x, 0.f); o0.y = fmaxf(acc[p][1] + bb0.y, 0.f);
      o0.z = fmaxf(acc[p][2] + bb0.z, 0.f); o0.w = fmaxf(acc[p][3] + bb0.w, 0.f);
      o1.x = fmaxf(acc[p][4] + bb1.x, 0.f); o1.y = fmaxf(acc[p][5] + bb1.y, 0.f);
      o1.z = fmaxf(acc[p][6] + bb1.z, 0.f); o1.w = fmaxf(acc[p][7] + bb1.w, 0.f);
      *(float4*)&H[row * HID + ct * 128 + tc * 4] = o0;
      *(float4*)&H[row * HID + ct * 128 + 64 + tc * 4] = o1;
    }
  }
  gbar(bar, 4);

  // ---- P5: mlp2 split-K partials (4 chunks of 128) ------------------------
  {
    float* wsm = (float*)smem;            // [64][64]  16384 B
    float* xs  = (float*)(smem + 16384);  // [64][129] 33024 B
    const int rt = bx >> 2, kc = bx & 3;
    const float* H = ws + OFF_H;
    const float* W2T = ws + OFF_W2T;
    float* part = ws + OFF_PART + (size_t)kc * (BATCH * 64);
    for (int e = tid; e < 64 * 32; e += 256) {
      const int row = e >> 5, i4 = e & 31;
      const float4 v =
          *(const float4*)&H[(size_t)(rt * 64 + row) * HID + kc * 128 + 4 * i4];
      float* d = &xs[row * 129 + 4 * i4];
      d[0] = v.x; d[1] = v.y; d[2] = v.z; d[3] = v.w;
    }
    const int tr = tid >> 4, tc = tid & 15;
    float acc[4][4] = {};
#pragma unroll
    for (int kh = 0; kh < 2; ++kh) {
      __syncthreads();
      for (int e = tid; e < 64 * 16; e += 256) {
        const int kk = e >> 4, c4 = e & 15;
        *(float4*)&wsm[kk * 64 + 4 * c4] =
            *(const float4*)&W2T[(size_t)(kc * 128 + kh * 64 + kk) * 64 + 4 * c4];
      }
      __syncthreads();
      const float* xk = xs + kh * 64;
#pragma unroll 4
      for (int kk = 0; kk < 64; ++kk) {
        const float4 bv = *(const float4*)&wsm[kk * 64 + tc * 4];
        const float a0 = xk[(tr * 4 + 0) * 129 + kk];
        const float a1 = xk[(tr * 4 + 1) * 129 + kk];
        const float a2 = xk[(tr * 4 + 2) * 129 + kk];
        const float a3 = xk[(tr * 4 + 3) * 129 + kk];
        acc[0][0] = fmaf(a0, bv.x, acc[0][0]); acc[0][1] = fmaf(a0, bv.y, acc[0][1]);
        acc[0][2] = fmaf(a0, bv.z, acc[0][2]); acc[0][3] = fmaf(a0, bv.w, acc[0][3]);
        acc[1][0] = fmaf(a1, bv.x, acc[1][0]); acc[1][1] = fmaf(a1, bv.y, acc[1][1]);
        acc[1][2] = fmaf(a1, bv.z, acc[1][2]); acc[1][3] = fmaf(a1, bv.w, acc[1][3]);
        acc[2][0] = fmaf(a2, bv.x, acc[2][0]); acc[2][1] = fmaf(a2, bv.y, acc[2][1]);
        acc[2][2] = fmaf(a2, bv.z, acc[2][2]); acc[2][3] = fmaf(a2, bv.w, acc[2][3]);
        acc[3][0] = fmaf(a3, bv.x, acc[3][0]); acc[3][1] = fmaf(a3, bv.y, acc[3][1]);
        acc[3][2] = fmaf(a3, bv.z, acc[3][2]); acc[3][3] = fmaf(a3, bv.w, acc[3][3]);
      }
    }
#pragma unroll
    for (int p = 0; p < 4; ++p) {
      float4 o;
      o.x = acc[p][0]; o.y = acc[p][1]; o.z = acc[p][2]; o.w = acc[p][3];
      *(float4*)&part[(size_t)(rt * 64 + tr * 4 + p) * 64 + tc * 4] = o;
    }
  }
  gbar(bar, 5);

  // ---- P6: reduce partials + b2 -> out ------------------------------------
  {
    const int i = bx * 256 + tid;          // 0..131071, one float4 each
    const int row = i >> 4, c4 = i & 15;
    const float* part = ws + OFF_PART;
    float4 s = *(const float4*)&part[(size_t)row * 64 + 4 * c4];
#pragma unroll
    for (int kc = 1; kc < 4; ++kc) {
      const float4 t =
          *(const float4*)&part[(size_t)kc * (BATCH * 64) + (size_t)row * 64 + 4 * c4];
      s.x += t.x; s.y += t.y; s.z += t.z; s.w += t.w;
    }
    const float4 bb = *(const float4*)&b2[4 * c4];
    float4 o;
    o.x = s.x + bb.x; o.y = s.y + bb.y; o.z = s.z + bb.z; o.w = s.w + bb.w;
    *(float4*)&out[(size_t)row * 64 + 4 * c4] = o;
  }
}

}  // namespace

extern "C" void kernel_launch(void* const* d_in, const int* in_sizes, int n_in,
                              void* d_out, int out_size, void* d_ws,
                              size_t ws_size, hipStream_t stream) {
  const float* E  = (const float*)d_in[0];
  const float* Wm = (const float*)d_in[1];
  const float* W1 = (const float*)d_in[2];
  const float* b1 = (const float*)d_in[3];
  const float* W2 = (const float*)d_in[4];
  const float* b2 = (const float*)d_in[5];
  const int* eids = (const int*)d_in[6];
  const int* mids = (const int*)d_in[7];
  float* out = (float*)d_out;
  float* ws = (float*)d_ws;

  // zero bucket counters + barrier slots (256 ints)
  hipMemsetAsync((char*)d_ws + OFF_CNT * sizeof(float), 0, 256 * sizeof(int),
                 stream);
  k_fused<<<dim3(GRID), dim3(256), 0, stream>>>(E, Wm, W1, b1, W2, b2, eids,
                                                mids, ws, out);
}

// Round 5
// 128.954 us; speedup vs baseline: 3.0660x; 3.0660x over previous
//
#include <hip/hip_runtime.h>

namespace {

constexpr int BATCH = 8192;
constexpr int EMB   = 128;
constexpr int HID   = 512;
constexpr int NMOD  = 64;
constexpr int CAP   = 256;   // Bin(8192,1/64) max ~170 << 256 (validated r1-r3)
constexpr float WB  = 1.0f / (7.0f * 0.5f);  // 2/7

// ws layout (float offsets)
constexpr size_t OFF_WT  = 0;                  // 64*128*128 [k][o]
constexpr size_t OFF_X0  = 1048576;            // 8192*128
constexpr size_t OFF_X1  = 2097152;            // 8192*128
constexpr size_t OFF_W1T = 3145728;            // 128*512  [k][col]
constexpr size_t OFF_W2T = 3211264;            // 512*64   [k][col]
constexpr size_t OFF_CNT = 3244032;            // 192 ints (zeroed by memset)
constexpr size_t OFF_BKT = 3244224;            // 3*64*CAP ints
// end ~13 MB << ws_size

// ---- prep: weight transposes + bucket scatter (one kernel, disjoint bx) ---
__global__ __launch_bounds__(256) void k_prep(const float* __restrict__ Wm,
                                              const float* __restrict__ W1,
                                              const float* __restrict__ W2,
                                              const int* __restrict__ mids,
                                              float* __restrict__ ws) {
  __shared__ float t[64 * 129];
  const int bx = blockIdx.x;
  const int tid = threadIdx.x;
  if (bx < 64) {  // W_mods[bx] [o][i] -> WT [i][o], two half-tiles
    const float* src = Wm + (size_t)bx * 16384;
    float* dst = ws + OFF_WT + (size_t)bx * 16384;
#pragma unroll
    for (int h = 0; h < 2; ++h) {
      if (h) __syncthreads();
      for (int e = tid; e < 64 * 128; e += 256) {
        const int o = e >> 7, i = e & 127;
        t[o * 129 + i] = src[(size_t)(h * 64 + o) * 128 + i];
      }
      __syncthreads();
      for (int e = tid; e < 128 * 64; e += 256) {
        const int i = e >> 6, oo = e & 63;
        dst[(size_t)i * 128 + h * 64 + oo] = t[oo * 129 + i];
      }
    }
  } else if (bx < 72) {  // W1 [512][128] -> W1T [128][512]
    const int j = bx - 64;
    for (int e = tid; e < 64 * 128; e += 256) {
      const int r = e >> 7, i = e & 127;
      t[r * 129 + i] = W1[(size_t)(j * 64 + r) * 128 + i];
    }
    __syncthreads();
    float* W1T = ws + OFF_W1T;
    for (int e = tid; e < 128 * 16; e += 256) {
      const int i = e >> 4, r4 = e & 15;
      float4 v;
      v.x = t[(4 * r4 + 0) * 129 + i];
      v.y = t[(4 * r4 + 1) * 129 + i];
      v.z = t[(4 * r4 + 2) * 129 + i];
      v.w = t[(4 * r4 + 3) * 129 + i];
      *(float4*)&W1T[(size_t)i * 512 + j * 64 + 4 * r4] = v;
    }
  } else if (bx < 80) {  // W2 [64][512] -> W2T [512][64]
    const int j = bx - 72;
    float* t2 = t;  // [64][65]
    for (int e = tid; e < 64 * 64; e += 256) {
      const int o = e >> 6, k = e & 63;
      t2[o * 65 + k] = W2[(size_t)o * 512 + j * 64 + k];
    }
    __syncthreads();
    float* W2T = ws + OFF_W2T;
    for (int e = tid; e < 64 * 16; e += 256) {
      const int k = e >> 4, o4 = e & 15;
      float4 v;
      v.x = t2[(4 * o4 + 0) * 65 + k];
      v.y = t2[(4 * o4 + 1) * 65 + k];
      v.z = t2[(4 * o4 + 2) * 65 + k];
      v.w = t2[(4 * o4 + 3) * 65 + k];
      *(float4*)&W2T[(size_t)(j * 64 + k) * 64 + 4 * o4] = v;
    }
  } else {  // bucket scatter (cnt pre-zeroed by hipMemsetAsync)
    const int idx = (bx - 80) * 256 + tid;
    if (idx < BATCH * 3) {
      const int b = idx / 3, h = idx - b * 3;
      const int m = mids[idx];
      int* cnt = (int*)(ws + OFF_CNT);
      int* bkt = (int*)(ws + OFF_BKT);
      const int pos = atomicAdd(&cnt[h * NMOD + m], 1);
      bkt[(h * NMOD + m) * CAP + pos] = b;
    }
  }
}

// ---- hop: per-module 64-row x 128-col tile, W streamed from L2 ------------
template <int HOP>
__global__ __launch_bounds__(256) void k_hop(const float* __restrict__ E,
                                             const int* __restrict__ eids,
                                             float* __restrict__ ws) {
  const int m = blockIdx.x >> 2, sl = blockIdx.x & 3;
  const int cn = ((const int*)(ws + OFF_CNT))[HOP * NMOD + m];
  const int r0 = sl * 64;
  if (r0 >= cn) return;
  const int nr = min(64, cn - r0);

  __shared__ float xs[64 * 129];
  __shared__ int rows[64];
  const int tid = threadIdx.x;
  const float* Wk = ws + OFF_WT + (size_t)m * 16384;  // [k][o]
  const int* bkt = (const int*)(ws + OFF_BKT) + (HOP * NMOD + m) * CAP + r0;
  const float* Xprev = ws + (HOP == 1 ? OFF_X0 : OFF_X1);
  float* Xnext = ws + (HOP == 1 ? OFF_X1 : OFF_X0);

  if (tid < nr) rows[tid] = bkt[tid];
  __syncthreads();
  for (int e = tid; e < 64 * 32; e += 256) {
    const int row = e >> 5, i4 = e & 31;
    if (row < nr) {
      const int b = rows[row];
      const float* src = (HOP == 0) ? (E + (size_t)eids[b * 4] * EMB)
                                    : (Xprev + (size_t)b * EMB);
      *(float4*)&xs[row * 129 + 4 * i4] = *(const float4*)&src[4 * i4];
    }
  }
  __syncthreads();

  const int tr = tid >> 4, tc = tid & 15;
  float acc[4][8] = {};
#pragma unroll 4
  for (int k = 0; k < 128; ++k) {
    const float4 w0 = *(const float4*)&Wk[(size_t)k * 128 + 4 * tc];
    const float4 w1 = *(const float4*)&Wk[(size_t)k * 128 + 64 + 4 * tc];
    const float a0 = xs[(tr * 4 + 0) * 129 + k];
    const float a1 = xs[(tr * 4 + 1) * 129 + k];
    const float a2 = xs[(tr * 4 + 2) * 129 + k];
    const float a3 = xs[(tr * 4 + 3) * 129 + k];
    acc[0][0] = fmaf(a0, w0.x, acc[0][0]); acc[0][1] = fmaf(a0, w0.y, acc[0][1]);
    acc[0][2] = fmaf(a0, w0.z, acc[0][2]); acc[0][3] = fmaf(a0, w0.w, acc[0][3]);
    acc[0][4] = fmaf(a0, w1.x, acc[0][4]); acc[0][5] = fmaf(a0, w1.y, acc[0][5]);
    acc[0][6] = fmaf(a0, w1.z, acc[0][6]); acc[0][7] = fmaf(a0, w1.w, acc[0][7]);
    acc[1][0] = fmaf(a1, w0.x, acc[1][0]); acc[1][1] = fmaf(a1, w0.y, acc[1][1]);
    acc[1][2] = fmaf(a1, w0.z, acc[1][2]); acc[1][3] = fmaf(a1, w0.w, acc[1][3]);
    acc[1][4] = fmaf(a1, w1.x, acc[1][4]); acc[1][5] = fmaf(a1, w1.y, acc[1][5]);
    acc[1][6] = fmaf(a1, w1.z, acc[1][6]); acc[1][7] = fmaf(a1, w1.w, acc[1][7]);
    acc[2][0] = fmaf(a2, w0.x, acc[2][0]); acc[2][1] = fmaf(a2, w0.y, acc[2][1]);
    acc[2][2] = fmaf(a2, w0.z, acc[2][2]); acc[2][3] = fmaf(a2, w0.w, acc[2][3]);
    acc[2][4] = fmaf(a2, w1.x, acc[2][4]); acc[2][5] = fmaf(a2, w1.y, acc[2][5]);
    acc[2][6] = fmaf(a2, w1.z, acc[2][6]); acc[2][7] = fmaf(a2, w1.w, acc[2][7]);
    acc[3][0] = fmaf(a3, w0.x, acc[3][0]); acc[3][1] = fmaf(a3, w0.y, acc[3][1]);
    acc[3][2] = fmaf(a3, w0.z, acc[3][2]); acc[3][3] = fmaf(a3, w0.w, acc[3][3]);
    acc[3][4] = fmaf(a3, w1.x, acc[3][4]); acc[3][5] = fmaf(a3, w1.y, acc[3][5]);
    acc[3][6] = fmaf(a3, w1.z, acc[3][6]); acc[3][7] = fmaf(a3, w1.w, acc[3][7]);
  }

#pragma unroll
  for (int p = 0; p < 4; ++p) {
    const int row = tr * 4 + p;
    if (row < nr) {
      const int b = rows[row];
      const float* bp = E + (size_t)eids[b * 4 + HOP + 1] * EMB;
      const float4 bias0 = *(const float4*)&bp[4 * tc];
      const float4 bias1 = *(const float4*)&bp[64 + 4 * tc];
      float4 o0, o1;
      o0.x = fmaxf(acc[p][0] + bias0.x, 0.f);
      o0.y = fmaxf(acc[p][1] + bias0.y, 0.f);
      o0.z = fmaxf(acc[p][2] + bias0.z, 0.f);
      o0.w = fmaxf(acc[p][3] + bias0.w, 0.f);
      o1.x = fmaxf(acc[p][4] + bias1.x, 0.f);
      o1.y = fmaxf(acc[p][5] + bias1.y, 0.f);
      o1.z = fmaxf(acc[p][6] + bias1.z, 0.f);
      o1.w = fmaxf(acc[p][7] + bias1.w, 0.f);
      if (HOP == 2) {
        o0.x = (1.f - WB) * bias0.x + WB * o0.x;
        o0.y = (1.f - WB) * bias0.y + WB * o0.y;
        o0.z = (1.f - WB) * bias0.z + WB * o0.z;
        o0.w = (1.f - WB) * bias0.w + WB * o0.w;
        o1.x = (1.f - WB) * bias1.x + WB * o1.x;
        o1.y = (1.f - WB) * bias1.y + WB * o1.y;
        o1.z = (1.f - WB) * bias1.z + WB * o1.z;
        o1.w = (1.f - WB) * bias1.w + WB * o1.w;
      }
      *(float4*)&Xnext[(size_t)b * EMB + 4 * tc] = o0;
      *(float4*)&Xnext[(size_t)b * EMB + 64 + 4 * tc] = o1;
    }
  }
}

// ---- fused MLP: 16 rows/block; H tile lives in LDS ------------------------
// phase A: H = relu(X @ W1T + b1)  (wave = 4 rows, 2 col-passes of 256)
// phase B: out = H @ W2T + b2      (wave = K-chunk of 128, LDS reduce)
constexpr int HS = 516;  // H LDS stride (2-way max aliasing = free)
__global__ __launch_bounds__(256) void k_mlp(const float* __restrict__ b1,
                                             const float* __restrict__ b2,
                                             float* __restrict__ ws,
                                             float* __restrict__ out) {
  __shared__ float xs[16 * 129];    //  8.25 KB
  __shared__ float hs[16 * HS];     // 33.0 KB
  __shared__ float part[4 * 1024];  // 16.4 KB
  const int tid = threadIdx.x;
  const int row0 = blockIdx.x * 16;
  const float* X = ws + OFF_X0;
  const float* W1T = ws + OFF_W1T;
  const float* W2T = ws + OFF_W2T;

  for (int e = tid; e < 16 * 32; e += 256) {
    const int row = e >> 5, i4 = e & 31;
    *(float4*)&xs[row * 129 + 4 * i4] =
        *(const float4*)&X[(size_t)(row0 + row) * EMB + 4 * i4];
  }
  __syncthreads();

  const int wv = tid >> 6, ln = tid & 63;
#pragma unroll
  for (int pass = 0; pass < 2; ++pass) {
    float acc[4][4] = {};
    const float* Wp = W1T + pass * 256 + 4 * ln;
#pragma unroll 4
    for (int k = 0; k < 128; ++k) {
      const float4 w = *(const float4*)&Wp[(size_t)k * 512];
      const float a0 = xs[(wv * 4 + 0) * 129 + k];
      const float a1 = xs[(wv * 4 + 1) * 129 + k];
      const float a2 = xs[(wv * 4 + 2) * 129 + k];
      const float a3 = xs[(wv * 4 + 3) * 129 + k];
      acc[0][0] = fmaf(a0, w.x, acc[0][0]); acc[0][1] = fmaf(a0, w.y, acc[0][1]);
      acc[0][2] = fmaf(a0, w.z, acc[0][2]); acc[0][3] = fmaf(a0, w.w, acc[0][3]);
      acc[1][0] = fmaf(a1, w.x, acc[1][0]); acc[1][1] = fmaf(a1, w.y, acc[1][1]);
      acc[1][2] = fmaf(a1, w.z, acc[1][2]); acc[1][3] = fmaf(a1, w.w, acc[1][3]);
      acc[2][0] = fmaf(a2, w.x, acc[2][0]); acc[2][1] = fmaf(a2, w.y, acc[2][1]);
      acc[2][2] = fmaf(a2, w.z, acc[2][2]); acc[2][3] = fmaf(a2, w.w, acc[2][3]);
      acc[3][0] = fmaf(a3, w.x, acc[3][0]); acc[3][1] = fmaf(a3, w.y, acc[3][1]);
      acc[3][2] = fmaf(a3, w.z, acc[3][2]); acc[3][3] = fmaf(a3, w.w, acc[3][3]);
    }
    const float4 bb = *(const float4*)&b1[pass * 256 + 4 * ln];
#pragma unroll
    for (int r = 0; r < 4; ++r) {
      float4 o;
      o.x = fmaxf(acc[r][0] + bb.x, 0.f);
      o.y = fmaxf(acc[r][1] + bb.y, 0.f);
      o.z = fmaxf(acc[r][2] + bb.z, 0.f);
      o.w = fmaxf(acc[r][3] + bb.w, 0.f);
      *(float4*)&hs[(wv * 4 + r) * HS + pass * 256 + 4 * ln] = o;
    }
  }
  __syncthreads();

  // phase B: wave wv handles k in [wv*128, wv*128+128)
  const int lr = ln >> 4, lc = ln & 15;
  float acc2[4][4] = {};
  const float* W2p = W2T + (size_t)wv * 128 * 64 + 4 * lc;
#pragma unroll 4
  for (int kk = 0; kk < 128; ++kk) {
    const int k = wv * 128 + kk;
    const float4 w = *(const float4*)&W2p[(size_t)kk * 64];
    const float a0 = hs[(lr * 4 + 0) * HS + k];
    const float a1 = hs[(lr * 4 + 1) * HS + k];
    const float a2 = hs[(lr * 4 + 2) * HS + k];
    const float a3 = hs[(lr * 4 + 3) * HS + k];
    acc2[0][0] = fmaf(a0, w.x, acc2[0][0]); acc2[0][1] = fmaf(a0, w.y, acc2[0][1]);
    acc2[0][2] = fmaf(a0, w.z, acc2[0][2]); acc2[0][3] = fmaf(a0, w.w, acc2[0][3]);
    acc2[1][0] = fmaf(a1, w.x, acc2[1][0]); acc2[1][1] = fmaf(a1, w.y, acc2[1][1]);
    acc2[1][2] = fmaf(a1, w.z, acc2[1][2]); acc2[1][3] = fmaf(a1, w.w, acc2[1][3]);
    acc2[2][0] = fmaf(a2, w.x, acc2[2][0]); acc2[2][1] = fmaf(a2, w.y, acc2[2][1]);
    acc2[2][2] = fmaf(a2, w.z, acc2[2][2]); acc2[2][3] = fmaf(a2, w.w, acc2[2][3]);
    acc2[3][0] = fmaf(a3, w.x, acc2[3][0]); acc2[3][1] = fmaf(a3, w.y, acc2[3][1]);
    acc2[3][2] = fmaf(a3, w.z, acc2[3][2]); acc2[3][3] = fmaf(a3, w.w, acc2[3][3]);
  }
#pragma unroll
  for (int r = 0; r < 4; ++r) {
    float4 pv;
    pv.x = acc2[r][0]; pv.y = acc2[r][1]; pv.z = acc2[r][2]; pv.w = acc2[r][3];
    *(float4*)&part[wv * 1024 + (lr * 4 + r) * 64 + 4 * lc] = pv;
  }
  __syncthreads();

  // reduce 4 partials + b2, one float4 per thread
  {
    const int r = tid >> 4, cf = tid & 15;
    float4 s = *(const float4*)&part[r * 64 + 4 * cf];
#pragma unroll
    for (int w = 1; w < 4; ++w) {
      const float4 t = *(const float4*)&part[w * 1024 + r * 64 + 4 * cf];
      s.x += t.x; s.y += t.y; s.z += t.z; s.w += t.w;
    }
    const float4 bb = *(const float4*)&b2[4 * cf];
    float4 o;
    o.x = s.x + bb.x; o.y = s.y + bb.y; o.z = s.z + bb.z; o.w = s.w + bb.w;
    *(float4*)&out[(size_t)(row0 + r) * 64 + 4 * cf] = o;
  }
}

}  // namespace

extern "C" void kernel_launch(void* const* d_in, const int* in_sizes, int n_in,
                              void* d_out, int out_size, void* d_ws,
                              size_t ws_size, hipStream_t stream) {
  const float* E  = (const float*)d_in[0];
  const float* Wm = (const float*)d_in[1];
  const float* W1 = (const float*)d_in[2];
  const float* b1 = (const float*)d_in[3];
  const float* W2 = (const float*)d_in[4];
  const float* b2 = (const float*)d_in[5];
  const int* eids = (const int*)d_in[6];
  const int* mids = (const int*)d_in[7];
  float* out = (float*)d_out;
  float* ws = (float*)d_ws;

  (void)hipMemsetAsync((char*)d_ws + OFF_CNT * sizeof(float), 0,
                       192 * sizeof(int), stream);
  k_prep<<<dim3(176), dim3(256), 0, stream>>>(Wm, W1, W2, mids, ws);
  k_hop<0><<<dim3(256), dim3(256), 0, stream>>>(E, eids, ws);
  k_hop<1><<<dim3(256), dim3(256), 0, stream>>>(E, eids, ws);
  k_hop<2><<<dim3(256), dim3(256), 0, stream>>>(E, eids, ws);
  k_mlp<<<dim3(512), dim3(256), 0, stream>>>(b1, b2, ws, out);
}